// Round 16
// baseline (711.764 us; speedup 1.0000x reference)
//
#include <hip/hip_runtime.h>
#include <cstdint>
#include <cstddef>

#define B_SZ 8
#define T_LEN 4096
#define HD 1024
#define MTOT (B_SZ * T_LEN)   // 32768 tokens

typedef unsigned short u16;
typedef __attribute__((ext_vector_type(8))) short bf16x8;
typedef __attribute__((ext_vector_type(8))) unsigned short us8;
typedef __attribute__((ext_vector_type(4))) float f32x4;
typedef __attribute__((ext_vector_type(16))) float f32x16;

static __device__ __forceinline__ float bf2f(u16 u) {
    union { unsigned i; float f; } v; v.i = ((unsigned)u) << 16; return v.f;
}
static __device__ __forceinline__ u16 f2bf(float f) {
    union { float f; unsigned i; } v; v.f = f;
    unsigned r = v.i + 0x7fffu + ((v.i >> 16) & 1u);
    return (u16)(r >> 16);
}
static __device__ __forceinline__ float sigm(float x) { return 1.f / (1.f + __expf(-x)); }
static __device__ __forceinline__ float tanh_fast(float x) { return 1.f - 2.f / (1.f + __expf(2.f * x)); }
static __device__ __forceinline__ float f4get(const float4& f, int k) {
    return k == 0 ? f.x : k == 1 ? f.y : k == 2 ? f.z : f.w;   // k static post-unroll
}

static __device__ __forceinline__ void gload_lds16(const void* g, void* l) {
    __builtin_amdgcn_global_load_lds((const __attribute__((address_space(1))) void*)g,
                                     (__attribute__((address_space(3))) void*)l, 16, 0, 0);
}

// ---- K0: weights f32 -> bf16: wcat = [v(1024); g(1024); t(1024); r(1024)], wob = Wo
__global__ __launch_bounds__(256) void prep_weights(
    const float* __restrict__ Wp, const float* __restrict__ Wg,
    const float* __restrict__ Wt, const float* __restrict__ Wr,
    const float* __restrict__ Wo, u16* __restrict__ wcat, u16* __restrict__ wob)
{
    int i = blockIdx.x * 256 + threadIdx.x;   // float4 index
    const int T1 = 4096 * 256;
    const int T2 = 1024 * 256;
    if (i < T1) {
        int r = i >> 8, kq = i & 255;
        float4 v;
        if      (r < 1024)  v = ((const float4*)Wp)[(size_t)(r + 1) * 256 + kq];   // v-rows: Wp[1..1024]
        else if (r < 2048)  v = ((const float4*)Wg)[(size_t)(r - 1024) * 256 + kq];
        else if (r < 3072)  v = ((const float4*)Wt)[(size_t)(r - 2048) * 256 + kq];
        else                v = ((const float4*)Wr)[(size_t)(r - 3072) * 256 + kq];
        ushort4 o; o.x = f2bf(v.x); o.y = f2bf(v.y); o.z = f2bf(v.z); o.w = f2bf(v.w);
        ((ushort4*)wcat)[i] = o;
    } else if (i < T1 + T2) {
        int j = i - T1;
        float4 v = ((const float4*)Wo)[j];
        ushort4 o; o.x = f2bf(v.x); o.y = f2bf(v.y); o.z = f2bf(v.z); o.w = f2bf(v.w);
        ((ushort4*)wob)[j] = o;
    }
}

// ---- K1: LayerNorm (f32) -> xn bf16, fused u[m] = xn_f32 . Wp[0] + bp[0] ----
__global__ __launch_bounds__(256) void ln_kernel(
    const float* __restrict__ x, const float* __restrict__ gamma,
    const float* __restrict__ beta, const float* __restrict__ Wp,
    const float* __restrict__ bp, u16* __restrict__ xnb, float* __restrict__ u)
{
    __shared__ float red[8];
    const int row = blockIdx.x, tid = threadIdx.x;
    const float4 v = ((const float4*)(x + (size_t)row * HD))[tid];
    float s  = v.x + v.y + v.z + v.w;
    float sq = v.x * v.x + v.y * v.y + v.z * v.z + v.w * v.w;
    #pragma unroll
    for (int off = 32; off > 0; off >>= 1) {
        s  += __shfl_down(s, off);
        sq += __shfl_down(sq, off);
    }
    if ((tid & 63) == 0) { red[tid >> 6] = s; red[4 + (tid >> 6)] = sq; }
    __syncthreads();
    const float S   = red[0] + red[1] + red[2] + red[3];
    const float SQ  = red[4] + red[5] + red[6] + red[7];
    const float mu  = S * (1.f / HD);
    const float var = SQ * (1.f / HD) - mu * mu;
    const float rs  = rsqrtf(var + 1e-5f);
    const float4 gg = ((const float4*)gamma)[tid];
    const float4 bb = ((const float4*)beta)[tid];
    const float x0 = (v.x - mu) * rs * gg.x + bb.x;
    const float x1 = (v.y - mu) * rs * gg.y + bb.y;
    const float x2 = (v.z - mu) * rs * gg.z + bb.z;
    const float x3 = (v.w - mu) * rs * gg.w + bb.w;
    ushort4 o; o.x = f2bf(x0); o.y = f2bf(x1); o.z = f2bf(x2); o.w = f2bf(x3);
    ((ushort4*)(xnb + (size_t)row * HD))[tid] = o;
    const float4 w0 = ((const float4*)Wp)[tid];
    float su = x0 * w0.x + x1 * w0.y + x2 * w0.z + x3 * w0.w;
    #pragma unroll
    for (int off = 32; off > 0; off >>= 1) su += __shfl_down(su, off);
    __syncthreads();
    if ((tid & 63) == 0) red[tid >> 6] = su;
    __syncthreads();
    if (tid == 0) u[row] = red[0] + red[1] + red[2] + red[3] + bp[0];
}

// ---- K2/K4: bf16 MFMA GEMM, 128x256 tile, 8 waves (2M x 4N, 64x64/wave),
// BK=32, 32x32x16 MFMA, dbuf 48 KiB LDS -> **2 independent blocks per CU**
// (16 waves/CU, separate barrier domains: one block's drain overlaps the
// other's compute — attacks the measured ~60% lockstep stall).
// Single-barrier pipelined K-loop (r14/r15-verified skeleton):
//   { vmcnt(0); s_barrier; sched_barrier(0); stage(t+1); 2 ks x (4 reads + 4 MFMA) }
// LDS swizzle (4-chunk rows): stored chunk cs of row r holds cg = cs ^ ((r>>1)&3)
//   -> bank-quad = 4(r&1) + cs' sweeps all 8 quads over 8 rows; per 16-lane
//   phase exactly 2 lanes/quad (r9/r11 construction, measured 0 conflicts).
// Read: cs = (ks*2 + khalf) ^ ((rl32>>1)&3), rl32 = lane&31, khalf = lane>>5.
// C/D 32x32 layout (m74/m101): col = lane&31, row = (r&3)+8*(r>>2)+4*khalf.
// MODE 0: swapped-operand MFMA -> transposed bf16 planes [d][MTOT].
// MODE 1: normal orientation, f32 [m][1024] store.
template<int MODE>
__global__ __launch_bounds__(512, 4) void gemm128x256(
    const u16* __restrict__ A, const u16* __restrict__ W,
    const float* __restrict__ bp,
    u16* __restrict__ Vt, u16* __restrict__ Gt, u16* __restrict__ Tt, u16* __restrict__ Rt,
    float* __restrict__ Cout)
{
    __shared__ u16 sA[2][128 * 32];   // 8 KiB per buf
    __shared__ u16 sB[2][256 * 32];   // 16 KiB per buf   => 48 KiB total
    const int mtile = blockIdx.x, ntile = blockIdx.y;
    const int tid = threadIdx.x;                 // 0..511
    const int lane = tid & 63, wave = tid >> 6;  // 8 waves
    const int wm = wave >> 2, wn = wave & 3;     // 2M x 4N of 64x64
    const u16* Ab = A + (size_t)mtile * 128 * 1024;
    const u16* Wb = W + (size_t)ntile * 256 * 1024;

    // staging: A-slab = 512 chunks (1/thread), B-slab = 1024 chunks (2/thread)
    int gA, lA, gB0, lB0, gB1, lB1;
    {
        const int q = tid;                       // A chunk 0..511
        const int r = q >> 2;                    // row 0..127
        gA = r * 1024 + ((q & 3) ^ ((r >> 1) & 3)) * 8;
        lA = q * 8;
    }
    {
        const int q0 = tid, r0 = q0 >> 2;        // B chunks
        gB0 = r0 * 1024 + ((q0 & 3) ^ ((r0 >> 1) & 3)) * 8;
        lB0 = q0 * 8;
        const int q1 = 512 + tid, r1 = q1 >> 2;
        gB1 = r1 * 1024 + ((q1 & 3) ^ ((r1 >> 1) & 3)) * 8;
        lB1 = q1 * 8;
    }
    auto stage = [&](int pb, int kt) {
        gload_lds16(Ab + gA  + kt * 32, &sA[pb][lA]);
        gload_lds16(Wb + gB0 + kt * 32, &sB[pb][lB0]);
        gload_lds16(Wb + gB1 + kt * 32, &sB[pb][lB1]);
    };

    f32x16 acc[2][2] = {};
    const int rl32  = lane & 31;                 // row-within-32
    const int khalf = lane >> 5;                 // k-half 0/1
    const int sw2   = (rl32 >> 1) & 3;           // swizzle key
    const int abase = (wm * 64 + rl32) * 32;     // u16 units (row stride 32)
    const int bbase = (wn * 64 + rl32) * 32;

    stage(0, 0);
    for (int t = 0; t < 32; ++t) {
        const int p = t & 1;
        asm volatile("s_waitcnt vmcnt(0)" ::: "memory");   // slab t (issued last iter) landed
        __builtin_amdgcn_s_barrier();                      // all waves' slab-t writes visible
        __builtin_amdgcn_sched_barrier(0);                 // nothing below crosses above barrier
        if (t < 31) stage(p ^ 1, t + 1);                   // buf last read at t-1, pre-barrier
        #pragma unroll
        for (int ks = 0; ks < 2; ++ks) {                   // two K=16 steps per slab
            const int cs = (ks * 2 + khalf) ^ sw2;
            bf16x8 aR[2], bR[2];
            #pragma unroll
            for (int sm = 0; sm < 2; ++sm)
                aR[sm] = *(const bf16x8*)(&sA[p][abase + sm * 1024 + cs * 8]);
            #pragma unroll
            for (int sn = 0; sn < 2; ++sn)
                bR[sn] = *(const bf16x8*)(&sB[p][bbase + sn * 1024 + cs * 8]);
            __builtin_amdgcn_s_setprio(1);
            #pragma unroll
            for (int sm = 0; sm < 2; ++sm)
                #pragma unroll
                for (int sn = 0; sn < 2; ++sn) {
                    if (MODE == 0)   // swapped operands -> D[d][m] (transposed)
                        acc[sm][sn] = __builtin_amdgcn_mfma_f32_32x32x16_bf16(bR[sn], aR[sm], acc[sm][sn], 0, 0, 0);
                    else
                        acc[sm][sn] = __builtin_amdgcn_mfma_f32_32x32x16_bf16(aR[sm], bR[sn], acc[sm][sn], 0, 0, 0);
                }
            __builtin_amdgcn_s_setprio(0);
        }
    }

    if (MODE == 1) {
        #pragma unroll
        for (int sm = 0; sm < 2; ++sm) {
            #pragma unroll
            for (int sn = 0; sn < 2; ++sn) {
                const int n = ntile * 256 + wn * 64 + sn * 32 + rl32;
                #pragma unroll
                for (int r = 0; r < 16; ++r) {
                    const int m = mtile * 128 + wm * 64 + sm * 32 + (r & 3) + 8 * (r >> 2) + 4 * khalf;
                    Cout[(size_t)m * 1024 + n] = acc[sm][sn][r];
                }
            }
        }
    } else {
        const int seg = ntile >> 2;               // 0:V 1:G 2:T 3:R (block-uniform)
        #pragma unroll
        for (int sn = 0; sn < 2; ++sn) {
            #pragma unroll
            for (int r = 0; r < 16; ++r) {
                const int d = (ntile & 3) * 256 + wn * 64 + sn * 32 + (r & 3) + 8 * (r >> 2) + 4 * khalf;
                const size_t drow = (size_t)d * MTOT;
                #pragma unroll
                for (int sm = 0; sm < 2; ++sm) {          // 64B-contiguous half-wave segments
                    const int m = mtile * 128 + wm * 64 + sm * 32 + rl32;
                    const float val = acc[sm][sn][r];
                    if (seg == 0) {
                        Vt[drow + m] = f2bf(val + bp[1 + d]);
                    } else if (seg == 1) {
                        Gt[drow + m] = f2bf(sigm(val));
                    } else if (seg == 2) {
                        Tt[drow + m] = f2bf(tanh_fast(val));
                    } else {
                        Rt[drow + m] = f2bf(sigm(val));
                    }
                }
            }
        }
    }
}

// ---- K3: LDS-free sequential dual cumsum, 8-slot ring / distance-6 prefetch --
// 128 blocks x 64 threads; lane owns one (b,d) chain. 6 chunks (384B/lane) in
// flight ~ 3.1 MB device-wide (vs r14's 1.5 MB) -> closes the BW-latency gap.
// All slot indices static post-unroll. u uses its own 4-slot / distance-3 ring.
__global__ __launch_bounds__(64) void scan_t(
    const u16* __restrict__ Vt, const u16* __restrict__ Gt,
    const u16* __restrict__ Tt, const u16* __restrict__ Rt,
    const float* __restrict__ ub, u16* __restrict__ outb,
    float* __restrict__ act_last, float* __restrict__ gho_last)
{
    const int lane = threadIdx.x;
    const int b  = blockIdx.x >> 4;
    const int d  = ((blockIdx.x & 15) << 6) + lane;
    const int bm0 = b * T_LEN;
    const size_t rbase = (size_t)d * MTOT + bm0;
    const us8* pv = (const us8*)(Vt + rbase);
    const us8* pg = (const us8*)(Gt + rbase);
    const us8* pt = (const us8*)(Tt + rbase);
    const us8* pr = (const us8*)(Rt + rbase);
    const float4* pu = (const float4*)(ub + bm0);   // block-uniform -> scalarized

    us8 sv[8][2], sg[8][2], st[8][2], sr[8][2];
    float4 su[4][4];

    #pragma unroll
    for (int c = 0; c < 6; ++c) {
        #pragma unroll
        for (int h = 0; h < 2; ++h) {
            sv[c][h] = pv[c * 2 + h]; sg[c][h] = pg[c * 2 + h];
            st[c][h] = pt[c * 2 + h]; sr[c][h] = pr[c * 2 + h];
        }
    }
    #pragma unroll
    for (int c = 0; c < 3; ++c) {
        #pragma unroll
        for (int q = 0; q < 4; ++q) su[c][q] = pu[c * 4 + q];
    }

    float acc_a = 0.f;
    _Float16 acc_g = (_Float16)0.f;

    for (int cq = 0; cq < 32; ++cq) {
        #pragma unroll
        for (int s = 0; s < 8; ++s) {                       // slot indices static
            const int c = cq * 8 + s;
            const int cn = c + 6;                           // stream prefetch dist 6
            const int sl = (s + 6) & 7;
            if (cn < 256) {
                #pragma unroll
                for (int h = 0; h < 2; ++h) {
                    sv[sl][h] = pv[cn * 2 + h]; sg[sl][h] = pg[cn * 2 + h];
                    st[sl][h] = pt[cn * 2 + h]; sr[sl][h] = pr[cn * 2 + h];
                }
            }
            const int cu = c + 3;                           // u prefetch dist 3
            const int ul = (s + 3) & 3;
            if (cu < 256) {
                #pragma unroll
                for (int q = 0; q < 4; ++q) su[ul][q] = pu[cu * 4 + q];
            }
            const int us_ = s & 3;
            #pragma unroll
            for (int e16 = 0; e16 < 16; ++e16) {
                const int h = e16 >> 3, e = e16 & 7;
                const float v  = bf2f(sv[s][h][e]);
                const float g  = bf2f(sg[s][h][e]);
                const float th = bf2f(st[s][h][e]);
                const float r  = bf2f(sr[s][h][e]);
                const float uu = f4get(su[us_][e16 >> 2], e16 & 3);
                acc_a = fmaf(uu, v, acc_a);                 // f32 sequential cumsum
                acc_g = acc_g + (_Float16)(g * th);         // fp16 RNE sequential cumsum
                const float comb = acc_a + (float)acc_g;
                outb[(size_t)(bm0 + c * 16 + e16) * HD + d] = f2bf(r * comb);
            }
        }
    }
    act_last[(size_t)b * HD + d] = acc_a;
    gho_last[(size_t)b * HD + d] = (float)acc_g;
}

extern "C" void kernel_launch(void* const* d_in, const int* in_sizes, int n_in,
                              void* d_out, int out_size, void* d_ws, size_t ws_size,
                              hipStream_t stream)
{
    const float* x   = (const float*)d_in[0];
    const float* gam = (const float*)d_in[1];
    const float* bet = (const float*)d_in[2];
    const float* Wp  = (const float*)d_in[3];
    const float* bp  = (const float*)d_in[4];
    const float* Wg  = (const float*)d_in[5];
    const float* Wt  = (const float*)d_in[6];
    const float* Wr  = (const float*)d_in[7];
    const float* Wo  = (const float*)d_in[8];

    float* out0     = (float*)d_out;                       // (B,T,H) f32
    float* act_last = out0 + (size_t)MTOT * HD;            // (B,D) f32
    float* gho_last = act_last + (size_t)B_SZ * HD;        // (B,D) fp16-valued f32

    char* ws = (char*)d_ws;
    const size_t SZ = (size_t)MTOT * HD * 2;               // 64 MiB per bf16 plane
    u16* xnb  = (u16*)(ws);                                // xn bf16; later scan output
    u16* Vt   = (u16*)(ws + SZ);                           // transposed planes [d][MTOT]
    u16* Gt   = (u16*)(ws + 2 * SZ);
    u16* Tt   = (u16*)(ws + 3 * SZ);
    u16* Rt   = (u16*)(ws + 4 * SZ);
    u16* wcat = (u16*)(ws + 5 * SZ);                       // 8,388,608 B
    u16* wob  = (u16*)(ws + 5 * SZ + 8388608);             // 2,097,152 B
    float* ub = (float*)(ws + 5 * SZ + 8388608 + 2097152); // 131,072 B

    prep_weights<<<5120, 256, 0, stream>>>(Wp, Wg, Wt, Wr, Wo, wcat, wob);
    ln_kernel<<<MTOT, 256, 0, stream>>>(x, gam, bet, Wp, bp, xnb, ub);
    gemm128x256<0><<<dim3(256, 16), 512, 0, stream>>>(xnb, wcat, bp, Vt, Gt, Tt, Rt, nullptr);
    scan_t<<<128, 64, 0, stream>>>(Vt, Gt, Tt, Rt, ub, xnb /*out*/, act_last, gho_last);
    gemm128x256<1><<<dim3(256, 4), 512, 0, stream>>>(xnb, wob, bp, nullptr, nullptr, nullptr, nullptr, out0);
}

// Round 17
// 589.896 us; speedup vs baseline: 1.2066x; 1.2066x over previous
//
#include <hip/hip_runtime.h>
#include <cstdint>
#include <cstddef>

#define B_SZ 8
#define T_LEN 4096
#define HD 1024
#define MTOT (B_SZ * T_LEN)   // 32768 tokens

typedef unsigned short u16;
typedef __attribute__((ext_vector_type(8))) short bf16x8;
typedef __attribute__((ext_vector_type(8))) unsigned short us8;
typedef __attribute__((ext_vector_type(4))) float f32x4;
typedef __attribute__((ext_vector_type(16))) float f32x16;

static __device__ __forceinline__ float bf2f(u16 u) {
    union { unsigned i; float f; } v; v.i = ((unsigned)u) << 16; return v.f;
}
static __device__ __forceinline__ u16 f2bf(float f) {
    union { float f; unsigned i; } v; v.f = f;
    unsigned r = v.i + 0x7fffu + ((v.i >> 16) & 1u);
    return (u16)(r >> 16);
}
static __device__ __forceinline__ float sigm(float x) { return 1.f / (1.f + __expf(-x)); }
static __device__ __forceinline__ float tanh_fast(float x) { return 1.f - 2.f / (1.f + __expf(2.f * x)); }
static __device__ __forceinline__ float f4get(const float4& f, int k) {
    return k == 0 ? f.x : k == 1 ? f.y : k == 2 ? f.z : f.w;   // k static post-unroll
}

static __device__ __forceinline__ void gload_lds16(const void* g, void* l) {
    __builtin_amdgcn_global_load_lds((const __attribute__((address_space(1))) void*)g,
                                     (__attribute__((address_space(3))) void*)l, 16, 0, 0);
}

// ---- K0: weights f32 -> bf16.
// wcat = [v(1024); g/t INTERLEAVED (2048: row 1024+2d = Wg[d], 1024+2d+1 = Wt[d]); r(1024)]
// wob = Wo
__global__ __launch_bounds__(256) void prep_weights(
    const float* __restrict__ Wp, const float* __restrict__ Wg,
    const float* __restrict__ Wt, const float* __restrict__ Wr,
    const float* __restrict__ Wo, u16* __restrict__ wcat, u16* __restrict__ wob)
{
    int i = blockIdx.x * 256 + threadIdx.x;   // float4 index
    const int T1 = 4096 * 256;
    const int T2 = 1024 * 256;
    if (i < T1) {
        int r = i >> 8, kq = i & 255;
        float4 v;
        if      (r < 1024)  v = ((const float4*)Wp)[(size_t)(r + 1) * 256 + kq];   // v-rows: Wp[1..1024]
        else if (r < 3072) {
            const int d = (r - 1024) >> 1;
            if (((r - 1024) & 1) == 0) v = ((const float4*)Wg)[(size_t)d * 256 + kq];
            else                       v = ((const float4*)Wt)[(size_t)d * 256 + kq];
        }
        else                v = ((const float4*)Wr)[(size_t)(r - 3072) * 256 + kq];
        ushort4 o; o.x = f2bf(v.x); o.y = f2bf(v.y); o.z = f2bf(v.z); o.w = f2bf(v.w);
        ((ushort4*)wcat)[i] = o;
    } else if (i < T1 + T2) {
        int j = i - T1;
        float4 v = ((const float4*)Wo)[j];
        ushort4 o; o.x = f2bf(v.x); o.y = f2bf(v.y); o.z = f2bf(v.z); o.w = f2bf(v.w);
        ((ushort4*)wob)[j] = o;
    }
}

// ---- K1: LayerNorm (f32) -> xn bf16, fused u[m] = xn_f32 . Wp[0] + bp[0] ----
__global__ __launch_bounds__(256) void ln_kernel(
    const float* __restrict__ x, const float* __restrict__ gamma,
    const float* __restrict__ beta, const float* __restrict__ Wp,
    const float* __restrict__ bp, u16* __restrict__ xnb, float* __restrict__ u)
{
    __shared__ float red[8];
    const int row = blockIdx.x, tid = threadIdx.x;
    const float4 v = ((const float4*)(x + (size_t)row * HD))[tid];
    float s  = v.x + v.y + v.z + v.w;
    float sq = v.x * v.x + v.y * v.y + v.z * v.z + v.w * v.w;
    #pragma unroll
    for (int off = 32; off > 0; off >>= 1) {
        s  += __shfl_down(s, off);
        sq += __shfl_down(sq, off);
    }
    if ((tid & 63) == 0) { red[tid >> 6] = s; red[4 + (tid >> 6)] = sq; }
    __syncthreads();
    const float S   = red[0] + red[1] + red[2] + red[3];
    const float SQ  = red[4] + red[5] + red[6] + red[7];
    const float mu  = S * (1.f / HD);
    const float var = SQ * (1.f / HD) - mu * mu;
    const float rs  = rsqrtf(var + 1e-5f);
    const float4 gg = ((const float4*)gamma)[tid];
    const float4 bb = ((const float4*)beta)[tid];
    const float x0 = (v.x - mu) * rs * gg.x + bb.x;
    const float x1 = (v.y - mu) * rs * gg.y + bb.y;
    const float x2 = (v.z - mu) * rs * gg.z + bb.z;
    const float x3 = (v.w - mu) * rs * gg.w + bb.w;
    ushort4 o; o.x = f2bf(x0); o.y = f2bf(x1); o.z = f2bf(x2); o.w = f2bf(x3);
    ((ushort4*)(xnb + (size_t)row * HD))[tid] = o;
    const float4 w0 = ((const float4*)Wp)[tid];
    float su = x0 * w0.x + x1 * w0.y + x2 * w0.z + x3 * w0.w;
    #pragma unroll
    for (int off = 32; off > 0; off >>= 1) su += __shfl_down(su, off);
    __syncthreads();
    if ((tid & 63) == 0) red[tid >> 6] = su;
    __syncthreads();
    if (tid == 0) u[row] = red[0] + red[1] + red[2] + red[3] + bp[0];
}

// ---- K2/K4: bf16 MFMA GEMM, 256x256 tile, 16 waves (4M x 4N, 64x64/wave),
// BK=64, 32x32x16 MFMA, dbuf 128 KiB LDS, r15-verified single-barrier K-loop.
// MODE 0 epilogue (transposed, swapped-operand):
//   ntile 0-3   -> V plane  (bf16, +bias)
//   ntile 4-11  -> P plane: fp16(sigm(g)*tanh(t)) — g/t are ADJACENT acc rows
//                  (wcat interleave puts g_d at even C-row, t_d at odd; the
//                  32x32 C/D layout rowfn(r)=(r&3)+8(r>>2)+4*khalf gives each
//                  lane the (2j,2j+1) row pairs in acc elems r=2j,2j+1)
//   ntile 12-15 -> R plane  (bf16, sigmoid)
// MODE 1: normal orientation, f32 [m][1024] store.
template<int MODE>
__global__ __launch_bounds__(1024, 4) void gemm256(
    const u16* __restrict__ A, const u16* __restrict__ W,
    const float* __restrict__ bp,
    u16* __restrict__ Vt, u16* __restrict__ Pt, u16* __restrict__ Rt,
    float* __restrict__ Cout)
{
    __shared__ u16 sA[2][256 * 64];   // 64 KiB
    __shared__ u16 sB[2][256 * 64];   // 64 KiB
    const int mtile = blockIdx.x, ntile = blockIdx.y;
    const int tid = threadIdx.x;
    const int lane = tid & 63, wave = tid >> 6;
    const int wm = wave >> 2, wn = wave & 3;     // 4M x 4N wave grid, 64x64 per wave
    const u16* Ab = A + (size_t)mtile * 256 * 1024;
    const u16* Wb = W + (size_t)ntile * 256 * 1024;

    // staging: slab = 2048 chunks (16B) per matrix; thread stages 2 chunks of A and B.
    int goff[2], loff[2];
    #pragma unroll
    for (int jj = 0; jj < 2; ++jj) {
        const int q = jj * 1024 + tid;           // chunk id 0..2047
        const int r = q >> 3;                    // row 0..255
        goff[jj] = r * 1024 + ((q & 7) ^ (r & 7)) * 8;
        loff[jj] = q * 8;
    }
    auto stage = [&](int pb, int kt) {
        #pragma unroll
        for (int jj = 0; jj < 2; ++jj) {
            gload_lds16(Ab + goff[jj] + kt * 64, &sA[pb][loff[jj]]);
            gload_lds16(Wb + goff[jj] + kt * 64, &sB[pb][loff[jj]]);
        }
    };

    f32x16 acc[2][2] = {};
    const int rl32  = lane & 31;                 // row-within-32
    const int khalf = lane >> 5;                 // k-half 0/1
    const int sw    = lane & 7;                  // swizzle key
    const int abase = (wm * 64 + rl32) * 64;     // u16 units
    const int bbase = (wn * 64 + rl32) * 64;

    stage(0, 0);
    for (int t = 0; t < 16; ++t) {
        const int p = t & 1;
        asm volatile("s_waitcnt vmcnt(0)" ::: "memory");   // slab t (issued last iter) landed
        __builtin_amdgcn_s_barrier();                      // all waves' slab-t writes visible
        __builtin_amdgcn_sched_barrier(0);                 // nothing below crosses above barrier
        if (t < 15) stage(p ^ 1, t + 1);                   // overwrites slab t-1's buf: readers done pre-barrier
        #pragma unroll
        for (int ks = 0; ks < 4; ++ks) {                   // four K=16 steps per slab
            const int cs = (ks * 2 + khalf) ^ sw;
            bf16x8 aR[2], bR[2];
            #pragma unroll
            for (int sm = 0; sm < 2; ++sm)
                aR[sm] = *(const bf16x8*)(&sA[p][abase + sm * 2048 + cs * 8]);
            #pragma unroll
            for (int sn = 0; sn < 2; ++sn)
                bR[sn] = *(const bf16x8*)(&sB[p][bbase + sn * 2048 + cs * 8]);
            __builtin_amdgcn_s_setprio(1);
            #pragma unroll
            for (int sm = 0; sm < 2; ++sm)
                #pragma unroll
                for (int sn = 0; sn < 2; ++sn) {
                    if (MODE == 0)   // swapped operands -> D[d][m] (transposed)
                        acc[sm][sn] = __builtin_amdgcn_mfma_f32_32x32x16_bf16(bR[sn], aR[sm], acc[sm][sn], 0, 0, 0);
                    else
                        acc[sm][sn] = __builtin_amdgcn_mfma_f32_32x32x16_bf16(aR[sm], bR[sn], acc[sm][sn], 0, 0, 0);
                }
            __builtin_amdgcn_s_setprio(0);
        }
    }

    if (MODE == 1) {
        #pragma unroll
        for (int sm = 0; sm < 2; ++sm) {
            #pragma unroll
            for (int sn = 0; sn < 2; ++sn) {
                const int n = ntile * 256 + wn * 64 + sn * 32 + rl32;
                #pragma unroll
                for (int r = 0; r < 16; ++r) {
                    const int m = mtile * 256 + wm * 64 + sm * 32 + (r & 3) + 8 * (r >> 2) + 4 * khalf;
                    Cout[(size_t)m * 1024 + n] = acc[sm][sn][r];
                }
            }
        }
    } else if (ntile < 4 || ntile >= 12) {
        const bool isV = (ntile < 4);
        #pragma unroll
        for (int sn = 0; sn < 2; ++sn) {
            #pragma unroll
            for (int r = 0; r < 16; ++r) {
                const int d = (ntile & 3) * 256 + wn * 64 + sn * 32 + (r & 3) + 8 * (r >> 2) + 4 * khalf;
                const size_t drow = (size_t)d * MTOT;
                #pragma unroll
                for (int sm = 0; sm < 2; ++sm) {          // two complete 64B lines per store
                    const int m = mtile * 256 + wm * 64 + sm * 32 + rl32;
                    const float val = acc[sm][sn][r];
                    if (isV) Vt[drow + m] = f2bf(val + bp[1 + d]);
                    else     Rt[drow + m] = f2bf(sigm(val));
                }
            }
        }
    } else {                                     // GT-fused: P = fp16(sigm(g)*tanh(t))
        #pragma unroll
        for (int sn = 0; sn < 2; ++sn) {
            #pragma unroll
            for (int j = 0; j < 8; ++j) {        // acc row pairs (2j, 2j+1)
                const int lrow = (ntile - 4) * 256 + wn * 64 + sn * 32
                               + ((2 * j) & 3) + 8 * (j >> 1) + 4 * khalf;   // even
                const int d = lrow >> 1;
                const size_t drow = (size_t)d * MTOT;
                #pragma unroll
                for (int sm = 0; sm < 2; ++sm) {
                    const int m = mtile * 256 + wm * 64 + sm * 32 + rl32;
                    union { u16 u; _Float16 h; } pc;
                    pc.h = (_Float16)(sigm(acc[sm][sn][2 * j]) * tanh_fast(acc[sm][sn][2 * j + 1]));
                    Pt[drow + m] = pc.u;
                }
            }
        }
    }
}

// ---- K3: LDS-free sequential dual cumsum, 3 streams (V, P-fp16, R), depth-3 --
// 128 blocks x 64 threads; lane owns one (b,d) chain; 4-slot ring (r14-verified),
// all slot indices static post-unroll. ghost = direct fp16 add of P.
__global__ __launch_bounds__(64) void scan_t(
    const u16* __restrict__ Vt, const u16* __restrict__ Pt,
    const u16* __restrict__ Rt,
    const float* __restrict__ ub, u16* __restrict__ outb,
    float* __restrict__ act_last, float* __restrict__ gho_last)
{
    const int lane = threadIdx.x;
    const int b  = blockIdx.x >> 4;
    const int d  = ((blockIdx.x & 15) << 6) + lane;
    const int bm0 = b * T_LEN;
    const size_t rbase = (size_t)d * MTOT + bm0;
    const us8* pv = (const us8*)(Vt + rbase);
    const us8* pp = (const us8*)(Pt + rbase);
    const us8* pr = (const us8*)(Rt + rbase);
    const float4* pu = (const float4*)(ub + bm0);   // block-uniform -> scalarized

    us8 sv[4][2], sp[4][2], sr[4][2];
    float4 su[4][4];

    #pragma unroll
    for (int c = 0; c < 3; ++c) {
        #pragma unroll
        for (int h = 0; h < 2; ++h) {
            sv[c][h] = pv[c * 2 + h]; sp[c][h] = pp[c * 2 + h]; sr[c][h] = pr[c * 2 + h];
        }
        #pragma unroll
        for (int q = 0; q < 4; ++q) su[c][q] = pu[c * 4 + q];
    }

    float acc_a = 0.f;
    _Float16 acc_g = (_Float16)0.f;

    for (int cq = 0; cq < 64; ++cq) {
        #pragma unroll
        for (int s = 0; s < 4; ++s) {                       // slot indices static
            const int c = cq * 4 + s;
            const int cn = c + 3;
            const int sl = (s + 3) & 3;
            if (cn < 256) {
                #pragma unroll
                for (int h = 0; h < 2; ++h) {
                    sv[sl][h] = pv[cn * 2 + h]; sp[sl][h] = pp[cn * 2 + h]; sr[sl][h] = pr[cn * 2 + h];
                }
                #pragma unroll
                for (int q = 0; q < 4; ++q) su[sl][q] = pu[cn * 4 + q];
            }
            #pragma unroll
            for (int e16 = 0; e16 < 16; ++e16) {
                const int h = e16 >> 3, e = e16 & 7;
                const float v  = bf2f(sv[s][h][e]);
                const float r  = bf2f(sr[s][h][e]);
                const float uu = f4get(su[s][e16 >> 2], e16 & 3);
                union { u16 u; _Float16 hh; } pc; pc.u = sp[s][h][e];
                acc_a = fmaf(uu, v, acc_a);                 // f32 sequential cumsum
                acc_g = acc_g + pc.hh;                      // fp16 RNE sequential cumsum
                const float comb = acc_a + (float)acc_g;
                outb[(size_t)(bm0 + c * 16 + e16) * HD + d] = f2bf(r * comb);
            }
        }
    }
    act_last[(size_t)b * HD + d] = acc_a;
    gho_last[(size_t)b * HD + d] = (float)acc_g;
}

extern "C" void kernel_launch(void* const* d_in, const int* in_sizes, int n_in,
                              void* d_out, int out_size, void* d_ws, size_t ws_size,
                              hipStream_t stream)
{
    const float* x   = (const float*)d_in[0];
    const float* gam = (const float*)d_in[1];
    const float* bet = (const float*)d_in[2];
    const float* Wp  = (const float*)d_in[3];
    const float* bp  = (const float*)d_in[4];
    const float* Wg  = (const float*)d_in[5];
    const float* Wt  = (const float*)d_in[6];
    const float* Wr  = (const float*)d_in[7];
    const float* Wo  = (const float*)d_in[8];

    float* out0     = (float*)d_out;                       // (B,T,H) f32
    float* act_last = out0 + (size_t)MTOT * HD;            // (B,D) f32
    float* gho_last = act_last + (size_t)B_SZ * HD;        // (B,D) fp16-valued f32

    char* ws = (char*)d_ws;
    const size_t SZ = (size_t)MTOT * HD * 2;               // 64 MiB per bf16 plane
    u16* xnb  = (u16*)(ws);                                // xn bf16; later scan output
    u16* Vt   = (u16*)(ws + SZ);                           // transposed planes [d][MTOT]
    u16* Pt   = (u16*)(ws + 2 * SZ);                       // fused fp16 g*t plane
    u16* Rt   = (u16*)(ws + 3 * SZ);
    u16* wcat = (u16*)(ws + 4 * SZ);                       // 8,388,608 B
    u16* wob  = (u16*)(ws + 4 * SZ + 8388608);             // 2,097,152 B
    float* ub = (float*)(ws + 4 * SZ + 8388608 + 2097152); // 131,072 B

    prep_weights<<<5120, 256, 0, stream>>>(Wp, Wg, Wt, Wr, Wo, wcat, wob);
    ln_kernel<<<MTOT, 256, 0, stream>>>(x, gam, bet, Wp, bp, xnb, ub);
    gemm256<0><<<dim3(128, 16), 1024, 0, stream>>>(xnb, wcat, bp, Vt, Pt, Rt, nullptr);
    scan_t<<<128, 64, 0, stream>>>(Vt, Pt, Rt, ub, xnb /*out*/, act_last, gho_last);
    gemm256<1><<<dim3(128, 4), 1024, 0, stream>>>(xnb, wob, bp, nullptr, nullptr, nullptr, out0);
}